// Round 6
// baseline (383.379 us; speedup 1.0000x reference)
//
#include <hip/hip_runtime.h>
#include <hip/hip_bf16.h>
#include <math.h>

#define N_NODES 50000
#define N_EDGES 400000
#define HEADS 6
#define DIMS 32
#define FEAT 192
#define NEG_SLOPE 0.2f

typedef __attribute__((ext_vector_type(8))) short short8;
typedef __attribute__((ext_vector_type(8))) unsigned short ushort8;
typedef __attribute__((ext_vector_type(4))) float f32x4;

__device__ __forceinline__ unsigned short f2bu(float f) {
    __hip_bfloat16 h = __float2bfloat16(f);
    unsigned short u; __builtin_memcpy(&u, &h, 2); return u;
}
__device__ __forceinline__ float bu2f(unsigned short u) {
    return __uint_as_float(((unsigned)u) << 16);
}

// ---------------- workspace layout (byte offsets) ----------------
#define XL_OFF   0           // ushort N*192   = 19,200,000
#define XR_OFF   19200000    // ushort N*192   = 19,200,000
#define WT_OFF   38400000    // short 384*192  = 147,456
#define BLR_OFF  38547456    // float 384      = 1,536
#define PAIR_OFF 38548992    // int2 E         = 3,200,000
#define DST_OFF  41748992    // int E          = 1,600,000
#define EXE_OFF  43348992    // float E*6      = 9,600,000
#define EXS_OFF  52948992    // float N*6      = 1,200,000
#define DEG_OFF  54148992    // int N          = 200,000
#define CUR_OFF  54348992    // int N
#define WSM_OFF  54548992    // float N
#define SCAN_OFF 54748992    // int N
#define BSUM_OFF 54948992    // int 256
#define BOFF_OFF 54950016    // int 256
#define NB_SCAN ((N_NODES + 255) / 256)   // 196

// ---------------- count + wsum + (fused) weight pack ----------------
__global__ __launch_bounds__(256) void k_count(const int* __restrict__ ei,
                                               const float* __restrict__ ew,
                                               int* __restrict__ deg,
                                               float* __restrict__ wsum,
                                               const float* __restrict__ Wl,
                                               const float* __restrict__ Wr,
                                               const float* __restrict__ bl,
                                               const float* __restrict__ br,
                                               short* __restrict__ Wt,
                                               float* __restrict__ blr) {
    int e = blockIdx.x * blockDim.x + threadIdx.x;
    if (e < N_EDGES) {
        int d = ei[N_EDGES + e];
        atomicAdd(&deg[d], 1);
        unsafeAtomicAdd(&wsum[d], ew[e]);
    }
    if (e < 384 * FEAT) {   // pack Wt[n][k] = W[k][n] (bf16)
        int n = e / FEAT, k = e - n * FEAT;
        float v = (n < FEAT) ? Wl[k * FEAT + n] : Wr[k * FEAT + (n - FEAT)];
        Wt[n * FEAT + k] = (short)f2bu(v);
    }
    if (e < 384) blr[e] = (e < FEAT) ? bl[e] : br[e - FEAT];
}

__global__ __launch_bounds__(256) void k_scan1(const int* __restrict__ deg,
                                               int* __restrict__ scan,
                                               int* __restrict__ bsums) {
    int t = threadIdx.x;
    int i = blockIdx.x * 256 + t;
    int v = (i < N_NODES) ? deg[i] : 0;
    __shared__ int s[256];
    s[t] = v; __syncthreads();
    for (int off = 1; off < 256; off <<= 1) {
        int u = (t >= off) ? s[t - off] : 0;
        __syncthreads();
        s[t] += u;
        __syncthreads();
    }
    if (i < N_NODES) scan[i] = s[t];   // inclusive within block
    if (t == 255) bsums[blockIdx.x] = s[255];
}

__global__ __launch_bounds__(256) void k_scan2(int* __restrict__ bsums,
                                               int* __restrict__ boffs) {
    int t = threadIdx.x;
    int v = (t < NB_SCAN) ? bsums[t] : 0;
    __shared__ int s[256];
    s[t] = v; __syncthreads();
    for (int off = 1; off < 256; off <<= 1) {
        int u = (t >= off) ? s[t - off] : 0;
        __syncthreads();
        s[t] += u;
        __syncthreads();
    }
    boffs[t] = s[t] - v;   // exclusive block offsets
}

// scatter edge payload (src, w) + dst into CSR slots
__global__ __launch_bounds__(256) void k_scatter(const int* __restrict__ ei,
                                                 const float* __restrict__ ew,
                                                 const int* __restrict__ scan,
                                                 const int* __restrict__ boffs,
                                                 const int* __restrict__ deg,
                                                 int* __restrict__ cursor,
                                                 int2* __restrict__ pair,
                                                 int* __restrict__ dstE) {
    int e = blockIdx.x * blockDim.x + threadIdx.x;
    if (e < N_EDGES) {
        int d = ei[N_EDGES + e];
        int st = scan[d] + boffs[d >> 8] - deg[d];
        int slot = atomicAdd(&cursor[d], 1);
        int2 p; p.x = ei[e]; p.y = __float_as_int(ew[e]);
        pair[st + slot] = p;
        dstE[st + slot] = d;
    }
}

// ---------------- MFMA GEMM: [xl|xr] = x @ [Wl|Wr] + [bl|br], bf16 out ----------------
__global__ __launch_bounds__(384) void k_gemm_mfma(const float* __restrict__ x,
                                                   const short* __restrict__ Wt,
                                                   const float* __restrict__ blr,
                                                   unsigned short* __restrict__ xl,
                                                   unsigned short* __restrict__ xr) {
    int wv   = threadIdx.x >> 6;
    int lane = threadIdx.x & 63;
    int m    = lane & 15;
    int kg   = lane >> 4;            // 0..3
    size_t row0 = (size_t)blockIdx.x * 16;
    int ncol0 = wv * 64;

    f32x4 acc0 = {0.f,0.f,0.f,0.f}, acc1 = acc0, acc2 = acc0, acc3 = acc0;

#pragma unroll
    for (int ks = 0; ks < 6; ks++) {
        int kb = ks * 32 + kg * 8;
        const float* ap = x + (row0 + m) * FEAT + kb;
        float4 a0 = *(const float4*)ap;
        float4 a1 = *(const float4*)(ap + 4);
        short8 af;
        af[0] = (short)f2bu(a0.x); af[1] = (short)f2bu(a0.y);
        af[2] = (short)f2bu(a0.z); af[3] = (short)f2bu(a0.w);
        af[4] = (short)f2bu(a1.x); af[5] = (short)f2bu(a1.y);
        af[6] = (short)f2bu(a1.z); af[7] = (short)f2bu(a1.w);
        const short* wp = Wt + (size_t)(ncol0 + m) * FEAT + kb;
        short8 b0 = *(const short8*)(wp);
        short8 b1 = *(const short8*)(wp + 16 * FEAT);
        short8 b2 = *(const short8*)(wp + 32 * FEAT);
        short8 b3 = *(const short8*)(wp + 48 * FEAT);
        acc0 = __builtin_amdgcn_mfma_f32_16x16x32_bf16(af, b0, acc0, 0, 0, 0);
        acc1 = __builtin_amdgcn_mfma_f32_16x16x32_bf16(af, b1, acc1, 0, 0, 0);
        acc2 = __builtin_amdgcn_mfma_f32_16x16x32_bf16(af, b2, acc2, 0, 0, 0);
        acc3 = __builtin_amdgcn_mfma_f32_16x16x32_bf16(af, b3, acc3, 0, 0, 0);
    }

    size_t orow = row0 + kg * 4;
    f32x4 accs[4] = {acc0, acc1, acc2, acc3};
#pragma unroll
    for (int t = 0; t < 4; t++) {
        int col = ncol0 + t * 16 + m;
        float bv = blr[col];
        unsigned short* dst = (col < FEAT) ? xl : xr;   // uniform per wave
        int c2 = (col < FEAT) ? col : col - FEAT;
#pragma unroll
        for (int r = 0; r < 4; r++) {
            dst[(orow + r) * FEAT + c2] = f2bu(accs[t][r] + bv);
        }
    }
}

// ---------------- edge-parallel alpha: one thread per (slot, head) ----------------
// slot < E: CSR edges. slot >= E: self-loops (w = wsum/deg).
__global__ __launch_bounds__(256) void k_alpha(const int2* __restrict__ pair,
                                               const int* __restrict__ dstE,
                                               const int* __restrict__ deg,
                                               const float* __restrict__ wsum,
                                               const float* __restrict__ att,
                                               const float* __restrict__ We,
                                               const unsigned short* __restrict__ xl,
                                               const unsigned short* __restrict__ xr,
                                               float* __restrict__ exE,
                                               float* __restrict__ exSelf) {
    __shared__ float satt[FEAT], sWe[FEAT];
    int t = threadIdx.x;
    if (t < FEAT) { satt[t] = att[t]; sWe[t] = We[t]; }
    __syncthreads();

    int gid = blockIdx.x * blockDim.x + t;
    if (gid >= (N_EDGES + N_NODES) * HEADS) return;
    int slot = gid / HEADS;
    int h = gid - slot * HEADS;

    int s, d; float w;
    if (slot < N_EDGES) {
        int2 p = pair[slot];
        s = p.x; w = __int_as_float(p.y);
        d = dstE[slot];
    } else {
        int n = slot - N_EDGES;
        s = n; d = n;
        w = wsum[n] / fmaxf((float)deg[n], 1.0f);
    }

    const ushort8* pl = (const ushort8*)(xl + (size_t)s * FEAT + h * DIMS);
    const ushort8* pr = (const ushort8*)(xr + (size_t)d * FEAT + h * DIMS);
    float alpha = 0.f;
#pragma unroll
    for (int q = 0; q < 4; q++) {
        ushort8 a8 = pl[q];
        ushort8 b8 = pr[q];
#pragma unroll
        for (int u = 0; u < 8; u++) {
            int c = q * 8 + u;
            float m = bu2f(a8[u]) + bu2f(b8[u]) + w * sWe[h * DIMS + c];
            m = (m > 0.f) ? m : NEG_SLOPE * m;
            alpha += m * satt[h * DIMS + c];
        }
    }
    float ex = __expf(alpha);
    if (slot < N_EDGES) exE[gid] = ex;
    else exSelf[gid - N_EDGES * HEADS] = ex;
}

// ---------------- per-node gather-accumulate (no shfl, no exp) ----------------
#define CHUNK 192
__global__ __launch_bounds__(192) void k_node(const float* __restrict__ x,
                                              const float* __restrict__ bias,
                                              const int* __restrict__ scan,
                                              const int* __restrict__ boffs,
                                              const int* __restrict__ deg,
                                              const int2* __restrict__ pair,
                                              const float* __restrict__ exE,
                                              const float* __restrict__ exSelf,
                                              const unsigned short* __restrict__ xl,
                                              float* __restrict__ out) {
    __shared__ int   sSrc[CHUNK];
    __shared__ float sEx[CHUNK * HEADS];
    int n = blockIdx.x;
    int j = threadIdx.x;
    int h = j >> 5;

    int dg  = deg[n];
    int beg = scan[n] + boffs[n >> 8] - dg;

    float acc = 0.f, den = 0.f;
    for (int i0 = 0; i0 < dg; i0 += CHUNK) {
        int c = dg - i0; if (c > CHUNK) c = CHUNK;
        if (j < c) sSrc[j] = pair[beg + i0 + j].x;
        int base = (beg + i0) * HEADS;
        for (int t = j; t < c * HEADS; t += 192) sEx[t] = exE[base + t];
        __syncthreads();
        float xln = bu2f(xl[(size_t)sSrc[0] * FEAT + j]);   // prefetch edge 0
        for (int i = 0; i < c; i++) {
            float xlv = xln;
            if (i + 1 < c) xln = bu2f(xl[(size_t)sSrc[i + 1] * FEAT + j]);
            float exv = sEx[i * HEADS + h];   // broadcast within head group
            acc += exv * xlv;
            den += exv;
        }
        __syncthreads();
    }
    // self-loop
    {
        float exv = exSelf[n * HEADS + h];
        float xlv = bu2f(xl[(size_t)n * FEAT + j]);
        acc += exv * xlv;
        den += exv;
    }

    float v = x[(size_t)n * FEAT + j] + bias[j] + acc / den;
    out[(size_t)n * FEAT + j] = v > 0.f ? v : 0.f;
}

extern "C" void kernel_launch(void* const* d_in, const int* in_sizes, int n_in,
                              void* d_out, int out_size, void* d_ws, size_t ws_size,
                              hipStream_t stream) {
    const float* x    = (const float*)d_in[0];
    const int*   ei   = (const int*)d_in[1];
    const float* ew   = (const float*)d_in[2];
    const float* Wl   = (const float*)d_in[3];
    const float* bl   = (const float*)d_in[4];
    const float* Wr   = (const float*)d_in[5];
    const float* br   = (const float*)d_in[6];
    const float* We   = (const float*)d_in[7];
    const float* att  = (const float*)d_in[8];
    const float* bias = (const float*)d_in[9];
    float* out = (float*)d_out;

    char* ws = (char*)d_ws;
    unsigned short* xl = (unsigned short*)(ws + XL_OFF);
    unsigned short* xr = (unsigned short*)(ws + XR_OFF);
    short* Wt     = (short*)(ws + WT_OFF);
    float* blr    = (float*)(ws + BLR_OFF);
    int2*  pair   = (int2*)(ws + PAIR_OFF);
    int*   dstE   = (int*)(ws + DST_OFF);
    float* exE    = (float*)(ws + EXE_OFF);
    float* exSelf = (float*)(ws + EXS_OFF);
    int*   deg    = (int*)(ws + DEG_OFF);
    int*   cursor = (int*)(ws + CUR_OFF);
    float* wsum   = (float*)(ws + WSM_OFF);
    int*   scan   = (int*)(ws + SCAN_OFF);
    int*   bsums  = (int*)(ws + BSUM_OFF);
    int*   boffs  = (int*)(ws + BOFF_OFF);

    // zero deg + cursor + wsum (contiguous); harness poisons ws with 0xAA
    hipMemsetAsync(ws + DEG_OFF, 0, 3 * N_NODES * sizeof(int), stream);

    k_count  <<<(N_EDGES + 255) / 256, 256, 0, stream>>>(ei, ew, deg, wsum,
                                                         Wl, Wr, bl, br, Wt, blr);
    k_scan1  <<<NB_SCAN, 256, 0, stream>>>(deg, scan, bsums);
    k_scan2  <<<1, 256, 0, stream>>>(bsums, boffs);
    k_scatter<<<(N_EDGES + 255) / 256, 256, 0, stream>>>(ei, ew, scan, boffs, deg,
                                                         cursor, pair, dstE);

    k_gemm_mfma<<<N_NODES / 16, 384, 0, stream>>>(x, Wt, blr, xl, xr);

    k_alpha<<<((N_EDGES + N_NODES) * HEADS + 255) / 256, 256, 0, stream>>>(
        pair, dstE, deg, wsum, att, We, xl, xr, exE, exSelf);

    k_node<<<N_NODES, 192, 0, stream>>>(x, bias, scan, boffs, deg,
                                        pair, exE, exSelf, xl, out);
}

// Round 7
// 355.589 us; speedup vs baseline: 1.0782x; 1.0782x over previous
//
#include <hip/hip_runtime.h>
#include <hip/hip_bf16.h>
#include <math.h>

#define N_NODES 50000
#define N_EDGES 400000
#define HEADS 6
#define DIMS 32
#define FEAT 192
#define NEG_SLOPE 0.2f

typedef __attribute__((ext_vector_type(8))) short short8;
typedef __attribute__((ext_vector_type(4))) float f32x4;

__device__ __forceinline__ unsigned short f2bu(float f) {
    __hip_bfloat16 h = __float2bfloat16(f);
    unsigned short u; __builtin_memcpy(&u, &h, 2); return u;
}
__device__ __forceinline__ float bu2f(unsigned short u) {
    return __uint_as_float(((unsigned)u) << 16);
}

// ---------------- workspace layout (byte offsets) ----------------
#define XL_OFF    0            // ushort N*192 = 19,200,000
#define XR_OFF    19200000     // ushort N*192
#define WT_OFF    38400000     // short 384*192 = 147,456
#define BLR_OFF   38547456     // float 384
#define PAIR_OFF  38548992     // int2 E = 3,200,000
#define DEG_OFF   41748992     // int N
#define CUR_OFF   41948992     // int N
#define WSM_OFF   42148992     // float N
#define SCAN_OFF  42348992     // int N
#define BSUM_OFF  42548992     // int 256
#define BOFF_OFF  42550016     // int 256
#define START_OFF 42551040     // int N+1
#define NB_SCAN ((N_NODES + 255) / 256)   // 196

// ---------------- count + wsum + (fused) weight pack ----------------
__global__ __launch_bounds__(256) void k_count(const int* __restrict__ ei,
                                               const float* __restrict__ ew,
                                               int* __restrict__ deg,
                                               float* __restrict__ wsum,
                                               const float* __restrict__ Wl,
                                               const float* __restrict__ Wr,
                                               const float* __restrict__ bl,
                                               const float* __restrict__ br,
                                               short* __restrict__ Wt,
                                               float* __restrict__ blr) {
    int e = blockIdx.x * blockDim.x + threadIdx.x;
    if (e < N_EDGES) {
        int d = ei[N_EDGES + e];
        atomicAdd(&deg[d], 1);
        unsafeAtomicAdd(&wsum[d], ew[e]);
    }
    if (e < 384 * FEAT) {   // pack Wt[n][k] = W[k][n] (bf16)
        int n = e / FEAT, k = e - n * FEAT;
        float v = (n < FEAT) ? Wl[k * FEAT + n] : Wr[k * FEAT + (n - FEAT)];
        Wt[n * FEAT + k] = (short)f2bu(v);
    }
    if (e < 384) blr[e] = (e < FEAT) ? bl[e] : br[e - FEAT];
}

__global__ __launch_bounds__(256) void k_scan1(const int* __restrict__ deg,
                                               int* __restrict__ scan,
                                               int* __restrict__ bsums) {
    int t = threadIdx.x;
    int i = blockIdx.x * 256 + t;
    int v = (i < N_NODES) ? deg[i] : 0;
    __shared__ int s[256];
    s[t] = v; __syncthreads();
    for (int off = 1; off < 256; off <<= 1) {
        int u = (t >= off) ? s[t - off] : 0;
        __syncthreads();
        s[t] += u;
        __syncthreads();
    }
    if (i < N_NODES) scan[i] = s[t];   // inclusive within block
    if (t == 255) bsums[blockIdx.x] = s[255];
}

__global__ __launch_bounds__(256) void k_scan2(int* __restrict__ bsums,
                                               int* __restrict__ boffs) {
    int t = threadIdx.x;
    int v = (t < NB_SCAN) ? bsums[t] : 0;
    __shared__ int s[256];
    s[t] = v; __syncthreads();
    for (int off = 1; off < 256; off <<= 1) {
        int u = (t >= off) ? s[t - off] : 0;
        __syncthreads();
        s[t] += u;
        __syncthreads();
    }
    boffs[t] = s[t] - v;   // exclusive block offsets
}

__global__ __launch_bounds__(256) void k_scan3(const int* __restrict__ scan,
                                               const int* __restrict__ boffs,
                                               const int* __restrict__ deg,
                                               int* __restrict__ start) {
    int i = blockIdx.x * blockDim.x + threadIdx.x;
    if (i < N_NODES) start[i] = scan[i] + boffs[i >> 8] - deg[i];
    if (i == 0) start[N_NODES] = N_EDGES;
}

// scatter edge payload (src, weight-bits) into CSR slots
__global__ __launch_bounds__(256) void k_scatter(const int* __restrict__ ei,
                                                 const float* __restrict__ ew,
                                                 const int* __restrict__ start,
                                                 int* __restrict__ cursor,
                                                 int2* __restrict__ pair) {
    int e = blockIdx.x * blockDim.x + threadIdx.x;
    if (e < N_EDGES) {
        int d = ei[N_EDGES + e];
        int slot = atomicAdd(&cursor[d], 1);
        int2 p; p.x = ei[e]; p.y = __float_as_int(ew[e]);
        pair[start[d] + slot] = p;
    }
}

// ---------------- MFMA GEMM: [xl|xr] = x @ [Wl|Wr] + [bl|br], bf16 out ----------------
__global__ __launch_bounds__(384) void k_gemm_mfma(const float* __restrict__ x,
                                                   const short* __restrict__ Wt,
                                                   const float* __restrict__ blr,
                                                   unsigned short* __restrict__ xl,
                                                   unsigned short* __restrict__ xr) {
    int wv   = threadIdx.x >> 6;
    int lane = threadIdx.x & 63;
    int m    = lane & 15;
    int kg   = lane >> 4;            // 0..3
    size_t row0 = (size_t)blockIdx.x * 16;
    int ncol0 = wv * 64;

    f32x4 acc0 = {0.f,0.f,0.f,0.f}, acc1 = acc0, acc2 = acc0, acc3 = acc0;

#pragma unroll
    for (int ks = 0; ks < 6; ks++) {
        int kb = ks * 32 + kg * 8;
        const float* ap = x + (row0 + m) * FEAT + kb;
        float4 a0 = *(const float4*)ap;
        float4 a1 = *(const float4*)(ap + 4);
        short8 af;
        af[0] = (short)f2bu(a0.x); af[1] = (short)f2bu(a0.y);
        af[2] = (short)f2bu(a0.z); af[3] = (short)f2bu(a0.w);
        af[4] = (short)f2bu(a1.x); af[5] = (short)f2bu(a1.y);
        af[6] = (short)f2bu(a1.z); af[7] = (short)f2bu(a1.w);
        const short* wp = Wt + (size_t)(ncol0 + m) * FEAT + kb;
        short8 b0 = *(const short8*)(wp);
        short8 b1 = *(const short8*)(wp + 16 * FEAT);
        short8 b2 = *(const short8*)(wp + 32 * FEAT);
        short8 b3 = *(const short8*)(wp + 48 * FEAT);
        acc0 = __builtin_amdgcn_mfma_f32_16x16x32_bf16(af, b0, acc0, 0, 0, 0);
        acc1 = __builtin_amdgcn_mfma_f32_16x16x32_bf16(af, b1, acc1, 0, 0, 0);
        acc2 = __builtin_amdgcn_mfma_f32_16x16x32_bf16(af, b2, acc2, 0, 0, 0);
        acc3 = __builtin_amdgcn_mfma_f32_16x16x32_bf16(af, b3, acc3, 0, 0, 0);
    }

    size_t orow = row0 + kg * 4;
    f32x4 accs[4] = {acc0, acc1, acc2, acc3};
#pragma unroll
    for (int t = 0; t < 4; t++) {
        int col = ncol0 + t * 16 + m;
        float bv = blr[col];
        unsigned short* dst = (col < FEAT) ? xl : xr;   // uniform per wave
        int c2 = (col < FEAT) ? col : col - FEAT;
#pragma unroll
        for (int r = 0; r < 4; r++) {
            dst[(orow + r) * FEAT + c2] = f2bu(accs[t][r] + bv);
        }
    }
}

// ---------------- fused node kernel: 8 nodes/block, LDS-staged edge rows ----------------
// Per chunk of 64 edges: (a) cooperative uint4 staging of xl rows (XOR-swizzled),
// (b) thread-per-(edge,head) alpha+exp from LDS, (c) thread-per-channel accumulate.
#define NPB 8
#define CEDGE 64
__global__ __launch_bounds__(192) void k_node(const float* __restrict__ x,
                                              const float* __restrict__ bias,
                                              const float* __restrict__ att,
                                              const float* __restrict__ We,
                                              const int* __restrict__ start,
                                              const int* __restrict__ deg,
                                              const float* __restrict__ wsum,
                                              const int2* __restrict__ pair,
                                              const unsigned short* __restrict__ xl,
                                              const unsigned short* __restrict__ xr,
                                              float* __restrict__ out) {
    __shared__ unsigned int sXL[CEDGE * 96];   // gathered xl rows, XOR-swizzled 16B blocks
    __shared__ unsigned int sXR[NPB * 96];     // xr rows of the 8 nodes (unswizzled)
    __shared__ unsigned int sXS[NPB * 96];     // xl rows of the 8 nodes (self-loop)
    __shared__ float sEx[CEDGE * HEADS];
    __shared__ float sExS[NPB * HEADS];
    __shared__ int   sSrc[CEDGE];
    __shared__ float sW[CEDGE];
    __shared__ int   sDst[CEDGE];
    __shared__ int   sStart[NPB + 1];
    __shared__ float sWm[NPB];
    __shared__ float sAtt[FEAT], sWeL[FEAT];

    int t = threadIdx.x;
    int h = t >> 5;
    int n0 = blockIdx.x * NPB;

    sAtt[t] = att[t];
    sWeL[t] = We[t];
    if (t <= NPB) sStart[t] = start[n0 + t];
    if (t < NPB) sWm[t] = wsum[n0 + t] / fmaxf((float)deg[n0 + t], 1.0f);
    {
        int nn = t / 24, p = t - nn * 24;   // 192 = 8 rows x 24 parts
        ((uint4*)&sXR[nn * 96 + p * 4])[0] = ((const uint4*)(xr + (size_t)(n0 + nn) * FEAT))[p];
        ((uint4*)&sXS[nn * 96 + p * 4])[0] = ((const uint4*)(xl + (size_t)(n0 + nn) * FEAT))[p];
    }
    __syncthreads();

    // self-loop alpha (48 threads)
    if (t < NPB * HEADS) {
        int nn = t / HEADS, hh = t - nn * HEADS;
        float w = sWm[nn];
        float alpha = 0.f;
#pragma unroll
        for (int c2 = 0; c2 < 16; c2++) {
            unsigned a = sXS[nn * 96 + hh * 16 + c2];
            unsigned b = sXR[nn * 96 + hh * 16 + c2];
            int j0 = hh * 32 + c2 * 2;
            float m0 = bu2f((unsigned short)a) + bu2f((unsigned short)b) + w * sWeL[j0];
            m0 = (m0 > 0.f) ? m0 : NEG_SLOPE * m0;
            alpha += m0 * sAtt[j0];
            float m1 = bu2f((unsigned short)(a >> 16)) + bu2f((unsigned short)(b >> 16)) + w * sWeL[j0 + 1];
            m1 = (m1 > 0.f) ? m1 : NEG_SLOPE * m1;
            alpha += m1 * sAtt[j0 + 1];
        }
        sExS[t] = __expf(alpha);
    }

    int gbase = sStart[0];
    int etot = sStart[NPB] - gbase;
    float acc[NPB], den[NPB];
#pragma unroll
    for (int nn = 0; nn < NPB; nn++) { acc[nn] = 0.f; den[nn] = 0.f; }

    for (int i0 = 0; i0 < etot; i0 += CEDGE) {
        int c = etot - i0; if (c > CEDGE) c = CEDGE;
        if (t < c) {
            int2 p = pair[gbase + i0 + t];
            sSrc[t] = p.x;
            sW[t] = __int_as_float(p.y);
        }
        if (t < NPB) {   // per-edge local dst index
            int lo = sStart[t] - gbase - i0;     if (lo < 0) lo = 0;
            int hi = sStart[t + 1] - gbase - i0; if (hi > c) hi = c;
            for (int q = lo; q < hi; q++) sDst[q] = t;
        }
        __syncthreads();
        // stage xl rows: 16B blocks, swizzled part index (p ^ (i&7)) to spread banks
        for (int q = t; q < c * 24; q += 192) {
            int i = q / 24, p = q - i * 24;
            ((uint4*)&sXL[i * 96 + ((p ^ (i & 7)) << 2)])[0] =
                ((const uint4*)(xl + (size_t)sSrc[i] * FEAT))[p];
        }
        __syncthreads();
        // alpha + exp: thread per (edge, head)
        for (int q = t; q < c * HEADS; q += 192) {
            int i = q / HEADS, hh = q - i * HEADS;
            int nn = sDst[i];
            float w = sW[i];
            float alpha = 0.f;
#pragma unroll
            for (int c2 = 0; c2 < 16; c2++) {
                unsigned a = sXL[i * 96 + (((hh << 4) + c2) ^ ((i & 7) << 2))];
                unsigned b = sXR[nn * 96 + (hh << 4) + c2];
                int j0 = hh * 32 + c2 * 2;
                float m0 = bu2f((unsigned short)a) + bu2f((unsigned short)b) + w * sWeL[j0];
                m0 = (m0 > 0.f) ? m0 : NEG_SLOPE * m0;
                alpha += m0 * sAtt[j0];
                float m1 = bu2f((unsigned short)(a >> 16)) + bu2f((unsigned short)(b >> 16)) + w * sWeL[j0 + 1];
                m1 = (m1 > 0.f) ? m1 : NEG_SLOPE * m1;
                alpha += m1 * sAtt[j0 + 1];
            }
            sEx[q] = __expf(alpha);
        }
        __syncthreads();
        // accumulate: thread per channel
#pragma unroll
        for (int nn = 0; nn < NPB; nn++) {
            int lo = sStart[nn] - gbase - i0;     if (lo < 0) lo = 0;
            int hi = sStart[nn + 1] - gbase - i0; if (hi > c) hi = c;
            for (int i = lo; i < hi; i++) {
                float ex = sEx[i * HEADS + h];
                unsigned u = sXL[i * 96 + (((t >> 1)) ^ ((i & 7) << 2))];
                unsigned short v = (t & 1) ? (unsigned short)(u >> 16) : (unsigned short)u;
                acc[nn] += ex * bu2f(v);
                den[nn] += ex;
            }
        }
        __syncthreads();
    }
    __syncthreads();   // ensure sExS visible even when etot == 0

    // epilogue: add self-loop, divide, residual + bias + relu
    float bj = bias[t];
#pragma unroll
    for (int nn = 0; nn < NPB; nn++) {
        float exS = sExS[nn * HEADS + h];
        unsigned u = sXS[nn * 96 + (t >> 1)];
        unsigned short v = (t & 1) ? (unsigned short)(u >> 16) : (unsigned short)u;
        float num = acc[nn] + exS * bu2f(v);
        float dn  = den[nn] + exS;
        size_t off = (size_t)(n0 + nn) * FEAT + t;
        float val = x[off] + bj + num / dn;
        out[off] = (val > 0.f) ? val : 0.f;
    }
}

extern "C" void kernel_launch(void* const* d_in, const int* in_sizes, int n_in,
                              void* d_out, int out_size, void* d_ws, size_t ws_size,
                              hipStream_t stream) {
    const float* x    = (const float*)d_in[0];
    const int*   ei   = (const int*)d_in[1];
    const float* ew   = (const float*)d_in[2];
    const float* Wl   = (const float*)d_in[3];
    const float* bl   = (const float*)d_in[4];
    const float* Wr   = (const float*)d_in[5];
    const float* br   = (const float*)d_in[6];
    const float* We   = (const float*)d_in[7];
    const float* att  = (const float*)d_in[8];
    const float* bias = (const float*)d_in[9];
    float* out = (float*)d_out;

    char* ws = (char*)d_ws;
    unsigned short* xl = (unsigned short*)(ws + XL_OFF);
    unsigned short* xr = (unsigned short*)(ws + XR_OFF);
    short* Wt     = (short*)(ws + WT_OFF);
    float* blr    = (float*)(ws + BLR_OFF);
    int2*  pair   = (int2*)(ws + PAIR_OFF);
    int*   deg    = (int*)(ws + DEG_OFF);
    int*   cursor = (int*)(ws + CUR_OFF);
    float* wsum   = (float*)(ws + WSM_OFF);
    int*   scan   = (int*)(ws + SCAN_OFF);
    int*   bsums  = (int*)(ws + BSUM_OFF);
    int*   boffs  = (int*)(ws + BOFF_OFF);
    int*   startp = (int*)(ws + START_OFF);

    // zero deg + cursor + wsum (contiguous); harness poisons ws with 0xAA
    hipMemsetAsync(ws + DEG_OFF, 0, 3 * N_NODES * sizeof(int), stream);

    k_count  <<<(N_EDGES + 255) / 256, 256, 0, stream>>>(ei, ew, deg, wsum,
                                                         Wl, Wr, bl, br, Wt, blr);
    k_scan1  <<<NB_SCAN, 256, 0, stream>>>(deg, scan, bsums);
    k_scan2  <<<1, 256, 0, stream>>>(bsums, boffs);
    k_scan3  <<<(N_NODES + 255) / 256, 256, 0, stream>>>(scan, boffs, deg, startp);
    k_scatter<<<(N_EDGES + 255) / 256, 256, 0, stream>>>(ei, ew, startp, cursor, pair);

    k_gemm_mfma<<<N_NODES / 16, 384, 0, stream>>>(x, Wt, blr, xl, xr);

    k_node<<<N_NODES / NPB, 192, 0, stream>>>(x, bias, att, We, startp, deg, wsum,
                                              pair, xl, xr, out);
}

// Round 8
// 330.821 us; speedup vs baseline: 1.1589x; 1.0749x over previous
//
#include <hip/hip_runtime.h>
#include <hip/hip_bf16.h>
#include <math.h>

#define N_NODES 50000
#define N_EDGES 400000
#define HEADS 6
#define DIMS 32
#define FEAT 192
#define NEG_SLOPE 0.2f

typedef __attribute__((ext_vector_type(8))) short short8;
typedef __attribute__((ext_vector_type(4))) float f32x4;

__device__ __forceinline__ unsigned short f2bu(float f) {
    __hip_bfloat16 h = __float2bfloat16(f);
    unsigned short u; __builtin_memcpy(&u, &h, 2); return u;
}
__device__ __forceinline__ float bu2f(unsigned short u) {
    return __uint_as_float(((unsigned)u) << 16);
}

// ---------------- workspace layout (byte offsets) ----------------
#define XL_OFF    0            // ushort N*192 = 19,200,000
#define XR_OFF    19200000     // ushort N*192
#define WT_OFF    38400000     // short 384*192 = 147,456
#define BLR_OFF   38547456     // float 384
#define PAIR_OFF  38548992     // int2 E = 3,200,000
#define DEG_OFF   41748992     // int N = 200,000
#define SCAN_OFF  41948992     // int N
#define BSUM_OFF  42148992     // int 256
#define BOFF_OFF  42150016     // int 256
#define START_OFF 42151040     // int N+1
#define NB_SCAN ((N_NODES + 255) / 256)   // 196

// ---------------- count (1 atomic/edge) + fused weight pack ----------------
__global__ __launch_bounds__(256) void k_count(const int* __restrict__ ei,
                                               int* __restrict__ deg,
                                               const float* __restrict__ Wl,
                                               const float* __restrict__ Wr,
                                               const float* __restrict__ bl,
                                               const float* __restrict__ br,
                                               short* __restrict__ Wt,
                                               float* __restrict__ blr) {
    int e = blockIdx.x * blockDim.x + threadIdx.x;
    if (e < N_EDGES) atomicAdd(&deg[ei[N_EDGES + e]], 1);
    if (e < 384 * FEAT) {   // pack Wt[n][k] = W[k][n] (bf16)
        int n = e / FEAT, k = e - n * FEAT;
        float v = (n < FEAT) ? Wl[k * FEAT + n] : Wr[k * FEAT + (n - FEAT)];
        Wt[n * FEAT + k] = (short)f2bu(v);
    }
    if (e < 384) blr[e] = (e < FEAT) ? bl[e] : br[e - FEAT];
}

__global__ __launch_bounds__(256) void k_scan1(const int* __restrict__ deg,
                                               int* __restrict__ scan,
                                               int* __restrict__ bsums) {
    int t = threadIdx.x;
    int i = blockIdx.x * 256 + t;
    int v = (i < N_NODES) ? deg[i] : 0;
    __shared__ int s[256];
    s[t] = v; __syncthreads();
    for (int off = 1; off < 256; off <<= 1) {
        int u = (t >= off) ? s[t - off] : 0;
        __syncthreads();
        s[t] += u;
        __syncthreads();
    }
    if (i < N_NODES) scan[i] = s[t];   // inclusive within block
    if (t == 255) bsums[blockIdx.x] = s[255];
}

__global__ __launch_bounds__(256) void k_scan2(int* __restrict__ bsums,
                                               int* __restrict__ boffs) {
    int t = threadIdx.x;
    int v = (t < NB_SCAN) ? bsums[t] : 0;
    __shared__ int s[256];
    s[t] = v; __syncthreads();
    for (int off = 1; off < 256; off <<= 1) {
        int u = (t >= off) ? s[t - off] : 0;
        __syncthreads();
        s[t] += u;
        __syncthreads();
    }
    boffs[t] = s[t] - v;   // exclusive block offsets
}

__global__ __launch_bounds__(256) void k_scan3(const int* __restrict__ scan,
                                               const int* __restrict__ boffs,
                                               const int* __restrict__ deg,
                                               int* __restrict__ start) {
    int i = blockIdx.x * blockDim.x + threadIdx.x;
    if (i < N_NODES) start[i] = scan[i] + boffs[i >> 8] - deg[i];
    if (i == 0) start[N_NODES] = N_EDGES;
}

// scatter edge payload into CSR slots; deg counts DOWN to zero (no cursor array)
__global__ __launch_bounds__(256) void k_scatter(const int* __restrict__ ei,
                                                 const float* __restrict__ ew,
                                                 const int* __restrict__ start,
                                                 int* __restrict__ deg,
                                                 int2* __restrict__ pair) {
    int e = blockIdx.x * blockDim.x + threadIdx.x;
    if (e < N_EDGES) {
        int d = ei[N_EDGES + e];
        int slot = atomicSub(&deg[d], 1) - 1;
        int2 p; p.x = ei[e]; p.y = __float_as_int(ew[e]);
        pair[start[d] + slot] = p;
    }
}

// ---------------- MFMA GEMM: [xl|xr] = x @ [Wl|Wr] + [bl|br], bf16 out ----------------
// LDS-transposed epilogue: MFMA C-layout -> LDS tile -> coalesced uint4 stores.
#define OSTRIDE 392   // ushorts per LDS row (392*2 % 128B != 0 -> bank spread; 16B aligned)
__global__ __launch_bounds__(384) void k_gemm_mfma(const float* __restrict__ x,
                                                   const short* __restrict__ Wt,
                                                   const float* __restrict__ blr,
                                                   unsigned short* __restrict__ xl,
                                                   unsigned short* __restrict__ xr) {
    __shared__ unsigned short sOut[16 * OSTRIDE];
    int wv   = threadIdx.x >> 6;
    int lane = threadIdx.x & 63;
    int m    = lane & 15;
    int kg   = lane >> 4;            // 0..3
    size_t row0 = (size_t)blockIdx.x * 16;
    int ncol0 = wv * 64;

    f32x4 acc0 = {0.f,0.f,0.f,0.f}, acc1 = acc0, acc2 = acc0, acc3 = acc0;

#pragma unroll
    for (int ks = 0; ks < 6; ks++) {
        int kb = ks * 32 + kg * 8;
        const float* ap = x + (row0 + m) * FEAT + kb;
        float4 a0 = *(const float4*)ap;
        float4 a1 = *(const float4*)(ap + 4);
        short8 af;
        af[0] = (short)f2bu(a0.x); af[1] = (short)f2bu(a0.y);
        af[2] = (short)f2bu(a0.z); af[3] = (short)f2bu(a0.w);
        af[4] = (short)f2bu(a1.x); af[5] = (short)f2bu(a1.y);
        af[6] = (short)f2bu(a1.z); af[7] = (short)f2bu(a1.w);
        const short* wp = Wt + (size_t)(ncol0 + m) * FEAT + kb;
        short8 b0 = *(const short8*)(wp);
        short8 b1 = *(const short8*)(wp + 16 * FEAT);
        short8 b2 = *(const short8*)(wp + 32 * FEAT);
        short8 b3 = *(const short8*)(wp + 48 * FEAT);
        acc0 = __builtin_amdgcn_mfma_f32_16x16x32_bf16(af, b0, acc0, 0, 0, 0);
        acc1 = __builtin_amdgcn_mfma_f32_16x16x32_bf16(af, b1, acc1, 0, 0, 0);
        acc2 = __builtin_amdgcn_mfma_f32_16x16x32_bf16(af, b2, acc2, 0, 0, 0);
        acc3 = __builtin_amdgcn_mfma_f32_16x16x32_bf16(af, b3, acc3, 0, 0, 0);
    }

    f32x4 accs[4] = {acc0, acc1, acc2, acc3};
#pragma unroll
    for (int t4 = 0; t4 < 4; t4++) {
        int col = ncol0 + t4 * 16 + m;
        float bv = blr[col];
#pragma unroll
        for (int r = 0; r < 4; r++) {
            sOut[(kg * 4 + r) * OSTRIDE + col] = f2bu(accs[t4][r] + bv);
        }
    }
    __syncthreads();
    // 16 rows x 384 ushorts -> 768 uint4 chunks, 2 per thread, fully coalesced
    for (int q = threadIdx.x; q < 768; q += 384) {
        int row = q / 48, p = q - row * 48;
        uint4 v = *(const uint4*)&sOut[row * OSTRIDE + p * 8];
        if (p < 24) *(uint4*)(xl + (row0 + row) * FEAT + p * 8) = v;
        else        *(uint4*)(xr + (row0 + row) * FEAT + (p - 24) * 8) = v;
    }
}

// ---------------- fused node kernel: 8 nodes/block, LDS-staged edge rows ----------------
// stride 100 uints (100 % 32 == 4): rows spread across banks, no swizzle needed.
#define NPB 8
#define CEDGE 32
#define RSTRIDE 100
__global__ __launch_bounds__(192) void k_node(const float* __restrict__ x,
                                              const float* __restrict__ bias,
                                              const float* __restrict__ att,
                                              const float* __restrict__ We,
                                              const int* __restrict__ start,
                                              const int2* __restrict__ pair,
                                              const unsigned short* __restrict__ xl,
                                              const unsigned short* __restrict__ xr,
                                              float* __restrict__ out) {
    __shared__ unsigned int sXL[CEDGE * RSTRIDE];   // gathered xl rows
    __shared__ unsigned int sXR[NPB * RSTRIDE];     // xr rows of the 8 nodes
    __shared__ unsigned int sXS[NPB * RSTRIDE];     // xl rows of the 8 nodes (self-loop)
    __shared__ float sEx[CEDGE * HEADS];
    __shared__ float sExS[NPB * HEADS];
    __shared__ int   sSrc[CEDGE];
    __shared__ float sW[CEDGE];
    __shared__ int   sDst[CEDGE];
    __shared__ int   sStart[NPB + 1];
    __shared__ float sAtt[FEAT], sWeL[FEAT];

    int t = threadIdx.x;
    int h = t >> 5;
    int n0 = blockIdx.x * NPB;

    sAtt[t] = att[t];
    sWeL[t] = We[t];
    if (t <= NPB) sStart[t] = start[n0 + t];
    {
        int nn = t / 24, p = t - nn * 24;   // 192 = 8 rows x 24 uint4 parts
        ((uint4*)&sXR[nn * RSTRIDE + p * 4])[0] = ((const uint4*)(xr + (size_t)(n0 + nn) * FEAT))[p];
        ((uint4*)&sXS[nn * RSTRIDE + p * 4])[0] = ((const uint4*)(xl + (size_t)(n0 + nn) * FEAT))[p];
    }
    __syncthreads();

    int gbase = sStart[0];
    int etot = sStart[NPB] - gbase;
    float acc[NPB], den[NPB], wsm[NPB];
#pragma unroll
    for (int nn = 0; nn < NPB; nn++) { acc[nn] = 0.f; den[nn] = 0.f; wsm[nn] = 0.f; }

    for (int i0 = 0; i0 < etot; i0 += CEDGE) {
        int c = etot - i0; if (c > CEDGE) c = CEDGE;
        if (t < c) {
            int2 p = pair[gbase + i0 + t];
            sSrc[t] = p.x;
            sW[t] = __int_as_float(p.y);
        }
        if (t < NPB) {   // per-edge local dst index
            int lo = sStart[t] - gbase - i0;     if (lo < 0) lo = 0;
            int hi = sStart[t + 1] - gbase - i0; if (hi > c) hi = c;
            for (int q = lo; q < hi; q++) sDst[q] = t;
        }
        __syncthreads();
        // stage xl rows: c*24 uint4 loads, 4 predicated steps -> MLP 4
        int nld = c * 24;
#pragma unroll
        for (int s = 0; s < 4; s++) {
            int q = t + s * 192;
            if (q < nld) {
                int i = q / 24, p = q - i * 24;
                ((uint4*)&sXL[i * RSTRIDE + p * 4])[0] =
                    ((const uint4*)(xl + (size_t)sSrc[i] * FEAT))[p];
            }
        }
        __syncthreads();
        // alpha + exp: thread per (edge, head)  (c*6 <= 192)
        if (t < c * HEADS) {
            int i = t / HEADS, hh = t - i * HEADS;
            int nn = sDst[i];
            float w = sW[i];
            float alpha = 0.f;
#pragma unroll
            for (int c2 = 0; c2 < 16; c2++) {
                unsigned a = sXL[i * RSTRIDE + (hh << 4) + c2];
                unsigned b = sXR[nn * RSTRIDE + (hh << 4) + c2];
                int j0 = hh * 32 + c2 * 2;
                float m0 = bu2f((unsigned short)a) + bu2f((unsigned short)b) + w * sWeL[j0];
                m0 = (m0 > 0.f) ? m0 : NEG_SLOPE * m0;
                alpha += m0 * sAtt[j0];
                float m1 = bu2f((unsigned short)(a >> 16)) + bu2f((unsigned short)(b >> 16)) + w * sWeL[j0 + 1];
                m1 = (m1 > 0.f) ? m1 : NEG_SLOPE * m1;
                alpha += m1 * sAtt[j0 + 1];
            }
            sEx[t] = __expf(alpha);
        }
        __syncthreads();
        // accumulate: thread per channel; also accumulate per-node weight sum
#pragma unroll
        for (int nn = 0; nn < NPB; nn++) {
            int lo = sStart[nn] - gbase - i0;     if (lo < 0) lo = 0;
            int hi = sStart[nn + 1] - gbase - i0; if (hi > c) hi = c;
            for (int i = lo; i < hi; i++) {
                float ex = sEx[i * HEADS + h];
                unsigned u = sXL[i * RSTRIDE + (t >> 1)];
                unsigned short v = (t & 1) ? (unsigned short)(u >> 16) : (unsigned short)u;
                acc[nn] += ex * bu2f(v);
                den[nn] += ex;
                wsm[nn] += sW[i];
            }
        }
        __syncthreads();
    }

    // self-loop alpha (after edge loop: needs wsm; uniform across threads)
    if (t < NPB * HEADS) {
        int nn = t / HEADS, hh = t - nn * HEADS;
        int dg = sStart[nn + 1] - sStart[nn];
        float w = wsm[nn] / fmaxf((float)dg, 1.0f);
        float alpha = 0.f;
#pragma unroll
        for (int c2 = 0; c2 < 16; c2++) {
            unsigned a = sXS[nn * RSTRIDE + (hh << 4) + c2];
            unsigned b = sXR[nn * RSTRIDE + (hh << 4) + c2];
            int j0 = hh * 32 + c2 * 2;
            float m0 = bu2f((unsigned short)a) + bu2f((unsigned short)b) + w * sWeL[j0];
            m0 = (m0 > 0.f) ? m0 : NEG_SLOPE * m0;
            alpha += m0 * sAtt[j0];
            float m1 = bu2f((unsigned short)(a >> 16)) + bu2f((unsigned short)(b >> 16)) + w * sWeL[j0 + 1];
            m1 = (m1 > 0.f) ? m1 : NEG_SLOPE * m1;
            alpha += m1 * sAtt[j0 + 1];
        }
        sExS[t] = __expf(alpha);
    }
    __syncthreads();

    // epilogue: add self-loop, divide, residual + bias + relu
    float bj = bias[t];
#pragma unroll
    for (int nn = 0; nn < NPB; nn++) {
        float exS = sExS[nn * HEADS + h];
        unsigned u = sXS[nn * RSTRIDE + (t >> 1)];
        unsigned short v = (t & 1) ? (unsigned short)(u >> 16) : (unsigned short)u;
        float num = acc[nn] + exS * bu2f(v);
        float dn  = den[nn] + exS;
        size_t off = (size_t)(n0 + nn) * FEAT + t;
        float val = x[off] + bj + num / dn;
        out[off] = (val > 0.f) ? val : 0.f;
    }
}

extern "C" void kernel_launch(void* const* d_in, const int* in_sizes, int n_in,
                              void* d_out, int out_size, void* d_ws, size_t ws_size,
                              hipStream_t stream) {
    const float* x    = (const float*)d_in[0];
    const int*   ei   = (const int*)d_in[1];
    const float* ew   = (const float*)d_in[2];
    const float* Wl   = (const float*)d_in[3];
    const float* bl   = (const float*)d_in[4];
    const float* Wr   = (const float*)d_in[5];
    const float* br   = (const float*)d_in[6];
    const float* We   = (const float*)d_in[7];
    const float* att  = (const float*)d_in[8];
    const float* bias = (const float*)d_in[9];
    float* out = (float*)d_out;

    char* ws = (char*)d_ws;
    unsigned short* xl = (unsigned short*)(ws + XL_OFF);
    unsigned short* xr = (unsigned short*)(ws + XR_OFF);
    short* Wt     = (short*)(ws + WT_OFF);
    float* blr    = (float*)(ws + BLR_OFF);
    int2*  pair   = (int2*)(ws + PAIR_OFF);
    int*   deg    = (int*)(ws + DEG_OFF);
    int*   scan   = (int*)(ws + SCAN_OFF);
    int*   bsums  = (int*)(ws + BSUM_OFF);
    int*   boffs  = (int*)(ws + BOFF_OFF);
    int*   startp = (int*)(ws + START_OFF);

    // zero deg; harness poisons ws with 0xAA
    hipMemsetAsync(ws + DEG_OFF, 0, N_NODES * sizeof(int), stream);

    k_count  <<<(N_EDGES + 255) / 256, 256, 0, stream>>>(ei, deg, Wl, Wr, bl, br, Wt, blr);
    k_scan1  <<<NB_SCAN, 256, 0, stream>>>(deg, scan, bsums);
    k_scan2  <<<1, 256, 0, stream>>>(bsums, boffs);
    k_scan3  <<<(N_NODES + 255) / 256, 256, 0, stream>>>(scan, boffs, deg, startp);
    k_scatter<<<(N_EDGES + 255) / 256, 256, 0, stream>>>(ei, ew, startp, deg, pair);

    k_gemm_mfma<<<N_NODES / 16, 384, 0, stream>>>(x, Wt, blr, xl, xr);

    k_node<<<N_NODES / NPB, 192, 0, stream>>>(x, bias, att, We, startp, pair, xl, xr, out);
}

// Round 9
// 328.237 us; speedup vs baseline: 1.1680x; 1.0079x over previous
//
#include <hip/hip_runtime.h>
#include <hip/hip_bf16.h>
#include <math.h>

#define N_NODES 50000
#define N_EDGES 400000
#define HEADS 6
#define DIMS 32
#define FEAT 192
#define NEG_SLOPE 0.2f

typedef __attribute__((ext_vector_type(8))) short short8;
typedef __attribute__((ext_vector_type(4))) float f32x4;

__device__ __forceinline__ unsigned short f2bu(float f) {
    __hip_bfloat16 h = __float2bfloat16(f);
    unsigned short u; __builtin_memcpy(&u, &h, 2); return u;
}
__device__ __forceinline__ float bu2f(unsigned short u) {
    return __uint_as_float(((unsigned)u) << 16);
}

// ---------------- workspace layout (byte offsets) ----------------
#define XL_OFF    0            // ushort N*192 = 19,200,000
#define XR_OFF    19200000     // ushort N*192
#define WT_OFF    38400000     // short 384*192 = 147,456
#define BLR_OFF   38547456     // float 384
#define COL_OFF   38548992     // int E = 1,600,000
#define DEG_OFF   40148992     // int N = 200,000
#define SCAN_OFF  40348992     // int N
#define BSUM_OFF  40548992     // int 256
#define BOFF_OFF  40550016     // int 256
#define NB_SCAN ((N_NODES + 255) / 256)   // 196

// ---------------- count (1 atomic/edge) + fused weight pack ----------------
__global__ __launch_bounds__(256) void k_count(const int* __restrict__ ei,
                                               int* __restrict__ deg,
                                               const float* __restrict__ Wl,
                                               const float* __restrict__ Wr,
                                               const float* __restrict__ bl,
                                               const float* __restrict__ br,
                                               short* __restrict__ Wt,
                                               float* __restrict__ blr) {
    int e = blockIdx.x * blockDim.x + threadIdx.x;
    if (e < N_EDGES) atomicAdd(&deg[ei[N_EDGES + e]], 1);
    if (e < 384 * FEAT) {   // pack Wt[n][k] = W[k][n] (bf16)
        int n = e / FEAT, k = e - n * FEAT;
        float v = (n < FEAT) ? Wl[k * FEAT + n] : Wr[k * FEAT + (n - FEAT)];
        Wt[n * FEAT + k] = (short)f2bu(v);
    }
    if (e < 384) blr[e] = (e < FEAT) ? bl[e] : br[e - FEAT];
}

__global__ __launch_bounds__(256) void k_scan1(const int* __restrict__ deg,
                                               int* __restrict__ scan,
                                               int* __restrict__ bsums) {
    int t = threadIdx.x;
    int i = blockIdx.x * 256 + t;
    int v = (i < N_NODES) ? deg[i] : 0;
    __shared__ int s[256];
    s[t] = v; __syncthreads();
    for (int off = 1; off < 256; off <<= 1) {
        int u = (t >= off) ? s[t - off] : 0;
        __syncthreads();
        s[t] += u;
        __syncthreads();
    }
    if (i < N_NODES) scan[i] = s[t];   // inclusive within block
    if (t == 255) bsums[blockIdx.x] = s[255];
}

__global__ __launch_bounds__(256) void k_scan2(int* __restrict__ bsums,
                                               int* __restrict__ boffs) {
    int t = threadIdx.x;
    int v = (t < NB_SCAN) ? bsums[t] : 0;
    __shared__ int s[256];
    s[t] = v; __syncthreads();
    for (int off = 1; off < 256; off <<= 1) {
        int u = (t >= off) ? s[t - off] : 0;
        __syncthreads();
        s[t] += u;
        __syncthreads();
    }
    boffs[t] = s[t] - v;   // exclusive block offsets
}

// ---------------- fused scatter + MFMA GEMM (block-range split) ----------------
// scatter blocks (first): col[inclEnd - atomicSub(deg)] = edge id (4B scatter)
// gemm blocks: [xl|xr] = x @ [Wl|Wr] + [bl|br] via 16x16x32 bf16 MFMA
#define SCAT_BLOCKS ((N_EDGES + 383) / 384)   // 1042
#define GEMM_BLOCKS (N_NODES / 16)            // 3125
#define OSTRIDE 392   // ushorts per LDS row
__global__ __launch_bounds__(384) void k_scatgemm(const int* __restrict__ ei,
                                                  const int* __restrict__ scan,
                                                  const int* __restrict__ boffs,
                                                  int* __restrict__ deg,
                                                  int* __restrict__ col,
                                                  const float* __restrict__ x,
                                                  const short* __restrict__ Wt,
                                                  const float* __restrict__ blr,
                                                  unsigned short* __restrict__ xl,
                                                  unsigned short* __restrict__ xr) {
    __shared__ unsigned short sOut[16 * OSTRIDE];
    if (blockIdx.x < SCAT_BLOCKS) {
        int e = blockIdx.x * 384 + threadIdx.x;
        if (e < N_EDGES) {
            int d = ei[N_EDGES + e];
            int inclEnd = boffs[d >> 8] + scan[d];
            int old = atomicSub(&deg[d], 1);     // old in [1, deg]
            col[inclEnd - old] = e;
        }
        return;
    }
    int wv   = threadIdx.x >> 6;
    int lane = threadIdx.x & 63;
    int m    = lane & 15;
    int kg   = lane >> 4;            // 0..3
    size_t row0 = (size_t)(blockIdx.x - SCAT_BLOCKS) * 16;
    int ncol0 = wv * 64;

    f32x4 acc0 = {0.f,0.f,0.f,0.f}, acc1 = acc0, acc2 = acc0, acc3 = acc0;

#pragma unroll
    for (int ks = 0; ks < 6; ks++) {
        int kb = ks * 32 + kg * 8;
        const float* ap = x + (row0 + m) * FEAT + kb;
        float4 a0 = *(const float4*)ap;
        float4 a1 = *(const float4*)(ap + 4);
        short8 af;
        af[0] = (short)f2bu(a0.x); af[1] = (short)f2bu(a0.y);
        af[2] = (short)f2bu(a0.z); af[3] = (short)f2bu(a0.w);
        af[4] = (short)f2bu(a1.x); af[5] = (short)f2bu(a1.y);
        af[6] = (short)f2bu(a1.z); af[7] = (short)f2bu(a1.w);
        const short* wp = Wt + (size_t)(ncol0 + m) * FEAT + kb;
        short8 b0 = *(const short8*)(wp);
        short8 b1 = *(const short8*)(wp + 16 * FEAT);
        short8 b2 = *(const short8*)(wp + 32 * FEAT);
        short8 b3 = *(const short8*)(wp + 48 * FEAT);
        acc0 = __builtin_amdgcn_mfma_f32_16x16x32_bf16(af, b0, acc0, 0, 0, 0);
        acc1 = __builtin_amdgcn_mfma_f32_16x16x32_bf16(af, b1, acc1, 0, 0, 0);
        acc2 = __builtin_amdgcn_mfma_f32_16x16x32_bf16(af, b2, acc2, 0, 0, 0);
        acc3 = __builtin_amdgcn_mfma_f32_16x16x32_bf16(af, b3, acc3, 0, 0, 0);
    }

    f32x4 accs[4] = {acc0, acc1, acc2, acc3};
#pragma unroll
    for (int t4 = 0; t4 < 4; t4++) {
        int cc = ncol0 + t4 * 16 + m;
        float bv = blr[cc];
#pragma unroll
        for (int r = 0; r < 4; r++) {
            sOut[(kg * 4 + r) * OSTRIDE + cc] = f2bu(accs[t4][r] + bv);
        }
    }
    __syncthreads();
    for (int q = threadIdx.x; q < 768; q += 384) {
        int row = q / 48, p = q - row * 48;
        uint4 v = *(const uint4*)&sOut[row * OSTRIDE + p * 8];
        if (p < 24) *(uint4*)(xl + (row0 + row) * FEAT + p * 8) = v;
        else        *(uint4*)(xr + (row0 + row) * FEAT + (p - 24) * 8) = v;
    }
}

// ---------------- fused node kernel: 8 nodes/block, LDS-staged edge rows ----------------
// Row layout: head hh at uint offset hh*20 (16 data + 4 pad); row stride 124.
// Head offsets mod 32 = {0,20,8,28,16,4} -> no 32-alias between heads in alpha phase.
#define NPB 8
#define CEDGE 32
#define RSTRIDE 124
#define HSTRIDE 20
__global__ __launch_bounds__(192) void k_node(const float* __restrict__ x,
                                              const float* __restrict__ bias,
                                              const float* __restrict__ att,
                                              const float* __restrict__ We,
                                              const int* __restrict__ scan,
                                              const int* __restrict__ boffs,
                                              const int* __restrict__ col,
                                              const int* __restrict__ ei,
                                              const float* __restrict__ ew,
                                              const unsigned short* __restrict__ xl,
                                              const unsigned short* __restrict__ xr,
                                              float* __restrict__ out) {
    __shared__ unsigned int sXL[CEDGE * RSTRIDE];   // gathered xl rows (head-padded)
    __shared__ unsigned int sXR[NPB * RSTRIDE];     // xr rows of the 8 nodes
    __shared__ unsigned int sXS[NPB * RSTRIDE];     // xl rows of the 8 nodes (self-loop)
    __shared__ float sEx[CEDGE * HEADS];
    __shared__ float sExS[NPB * HEADS];
    __shared__ int   sSrc[CEDGE];
    __shared__ float sW[CEDGE];
    __shared__ int   sDst[CEDGE];
    __shared__ int   sStart[NPB + 1];
    __shared__ float sAtt[FEAT], sWeL[FEAT];

    int t = threadIdx.x;
    int h = t >> 5;
    int n0 = blockIdx.x * NPB;

    sAtt[t] = att[t];
    sWeL[t] = We[t];
    if (t <= NPB) {   // exclusive start from scan/boffs (no start array)
        int n = n0 + t;
        int st;
        if (n >= N_NODES) st = N_EDGES;
        else {
            int b = n >> 8;
            st = boffs[b] + ((n & 255) ? scan[n - 1] : 0);
        }
        sStart[t] = st;
    }
    {
        int nn = t / 24, p = t - nn * 24;   // p: uint4 part; head p>>2, sub p&3
        int off = nn * RSTRIDE + (p >> 2) * HSTRIDE + (p & 3) * 4;
        ((uint4*)&sXR[off])[0] = ((const uint4*)(xr + (size_t)(n0 + nn) * FEAT))[p];
        ((uint4*)&sXS[off])[0] = ((const uint4*)(xl + (size_t)(n0 + nn) * FEAT))[p];
    }
    __syncthreads();

    int gbase = sStart[0];
    int etot = sStart[NPB] - gbase;
    float acc[NPB], den[NPB], wsm[NPB];
#pragma unroll
    for (int nn = 0; nn < NPB; nn++) { acc[nn] = 0.f; den[nn] = 0.f; wsm[nn] = 0.f; }

    for (int i0 = 0; i0 < etot; i0 += CEDGE) {
        int c = etot - i0; if (c > CEDGE) c = CEDGE;
        if (t < c) {
            int e = col[gbase + i0 + t];
            sSrc[t] = ei[e];
            sW[t] = ew[e];
        }
        if (t < NPB) {   // per-edge local dst index
            int lo = sStart[t] - gbase - i0;     if (lo < 0) lo = 0;
            int hi = sStart[t + 1] - gbase - i0; if (hi > c) hi = c;
            for (int q = lo; q < hi; q++) sDst[q] = t;
        }
        __syncthreads();
        // stage xl rows into head-padded layout; MLP 4
        int nld = c * 24;
#pragma unroll
        for (int s = 0; s < 4; s++) {
            int q = t + s * 192;
            if (q < nld) {
                int i = q / 24, p = q - i * 24;
                int off = i * RSTRIDE + (p >> 2) * HSTRIDE + (p & 3) * 4;
                ((uint4*)&sXL[off])[0] = ((const uint4*)(xl + (size_t)sSrc[i] * FEAT))[p];
            }
        }
        __syncthreads();
        // alpha + exp: thread per (edge, head)  (c*6 <= 192)
        if (t < c * HEADS) {
            int i = t / HEADS, hh = t - i * HEADS;
            int nn = sDst[i];
            float w = sW[i];
            float alpha = 0.f;
#pragma unroll
            for (int c2 = 0; c2 < 16; c2++) {
                unsigned a = sXL[i * RSTRIDE + hh * HSTRIDE + c2];
                unsigned b = sXR[nn * RSTRIDE + hh * HSTRIDE + c2];
                int j0 = hh * 32 + c2 * 2;
                float m0 = bu2f((unsigned short)a) + bu2f((unsigned short)b) + w * sWeL[j0];
                m0 = (m0 > 0.f) ? m0 : NEG_SLOPE * m0;
                alpha += m0 * sAtt[j0];
                float m1 = bu2f((unsigned short)(a >> 16)) + bu2f((unsigned short)(b >> 16)) + w * sWeL[j0 + 1];
                m1 = (m1 > 0.f) ? m1 : NEG_SLOPE * m1;
                alpha += m1 * sAtt[j0 + 1];
            }
            sEx[t] = __expf(alpha);
        }
        __syncthreads();
        // accumulate: thread per channel; also per-node weight sum
        int cidx = h * HSTRIDE + ((t & 31) >> 1);
#pragma unroll
        for (int nn = 0; nn < NPB; nn++) {
            int lo = sStart[nn] - gbase - i0;     if (lo < 0) lo = 0;
            int hi = sStart[nn + 1] - gbase - i0; if (hi > c) hi = c;
            for (int i = lo; i < hi; i++) {
                float ex = sEx[i * HEADS + h];
                unsigned u = sXL[i * RSTRIDE + cidx];
                unsigned short v = (t & 1) ? (unsigned short)(u >> 16) : (unsigned short)u;
                acc[nn] += ex * bu2f(v);
                den[nn] += ex;
                wsm[nn] += sW[i];
            }
        }
        __syncthreads();
    }

    // self-loop alpha (needs wsm, uniform across threads)
    if (t < NPB * HEADS) {
        int nn = t / HEADS, hh = t - nn * HEADS;
        int dg = sStart[nn + 1] - sStart[nn];
        float w = wsm[nn] / fmaxf((float)dg, 1.0f);
        float alpha = 0.f;
#pragma unroll
        for (int c2 = 0; c2 < 16; c2++) {
            unsigned a = sXS[nn * RSTRIDE + hh * HSTRIDE + c2];
            unsigned b = sXR[nn * RSTRIDE + hh * HSTRIDE + c2];
            int j0 = hh * 32 + c2 * 2;
            float m0 = bu2f((unsigned short)a) + bu2f((unsigned short)b) + w * sWeL[j0];
            m0 = (m0 > 0.f) ? m0 : NEG_SLOPE * m0;
            alpha += m0 * sAtt[j0];
            float m1 = bu2f((unsigned short)(a >> 16)) + bu2f((unsigned short)(b >> 16)) + w * sWeL[j0 + 1];
            m1 = (m1 > 0.f) ? m1 : NEG_SLOPE * m1;
            alpha += m1 * sAtt[j0 + 1];
        }
        sExS[t] = __expf(alpha);
    }
    __syncthreads();

    // epilogue: add self-loop, divide, residual + bias + relu
    float bj = bias[t];
    int cidx = h * HSTRIDE + ((t & 31) >> 1);
#pragma unroll
    for (int nn = 0; nn < NPB; nn++) {
        float exS = sExS[nn * HEADS + h];
        unsigned u = sXS[nn * RSTRIDE + cidx];
        unsigned short v = (t & 1) ? (unsigned short)(u >> 16) : (unsigned short)u;
        float num = acc[nn] + exS * bu2f(v);
        float dn  = den[nn] + exS;
        size_t off = (size_t)(n0 + nn) * FEAT + t;
        float val = x[off] + bj + num / dn;
        out[off] = (val > 0.f) ? val : 0.f;
    }
}

extern "C" void kernel_launch(void* const* d_in, const int* in_sizes, int n_in,
                              void* d_out, int out_size, void* d_ws, size_t ws_size,
                              hipStream_t stream) {
    const float* x    = (const float*)d_in[0];
    const int*   ei   = (const int*)d_in[1];
    const float* ew   = (const float*)d_in[2];
    const float* Wl   = (const float*)d_in[3];
    const float* bl   = (const float*)d_in[4];
    const float* Wr   = (const float*)d_in[5];
    const float* br   = (const float*)d_in[6];
    const float* We   = (const float*)d_in[7];
    const float* att  = (const float*)d_in[8];
    const float* bias = (const float*)d_in[9];
    float* out = (float*)d_out;

    char* ws = (char*)d_ws;
    unsigned short* xl = (unsigned short*)(ws + XL_OFF);
    unsigned short* xr = (unsigned short*)(ws + XR_OFF);
    short* Wt     = (short*)(ws + WT_OFF);
    float* blr    = (float*)(ws + BLR_OFF);
    int*   col    = (int*)(ws + COL_OFF);
    int*   deg    = (int*)(ws + DEG_OFF);
    int*   scan   = (int*)(ws + SCAN_OFF);
    int*   bsums  = (int*)(ws + BSUM_OFF);
    int*   boffs  = (int*)(ws + BOFF_OFF);

    // zero deg; harness poisons ws with 0xAA
    hipMemsetAsync(ws + DEG_OFF, 0, N_NODES * sizeof(int), stream);

    k_count<<<(N_EDGES + 255) / 256, 256, 0, stream>>>(ei, deg, Wl, Wr, bl, br, Wt, blr);
    k_scan1<<<NB_SCAN, 256, 0, stream>>>(deg, scan, bsums);
    k_scan2<<<1, 256, 0, stream>>>(bsums, boffs);

    k_scatgemm<<<SCAT_BLOCKS + GEMM_BLOCKS, 384, 0, stream>>>(ei, scan, boffs, deg, col,
                                                              x, Wt, blr, xl, xr);

    k_node<<<N_NODES / NPB, 192, 0, stream>>>(x, bias, att, We, scan, boffs,
                                              col, ei, ew, xl, xr, out);
}